// Round 1
// baseline (1781.952 us; speedup 1.0000x reference)
//
#include <hip/hip_runtime.h>
#include <hip/hip_bf16.h>

typedef __attribute__((ext_vector_type(8))) short short8;
typedef __attribute__((ext_vector_type(4))) short short4v;
typedef __attribute__((ext_vector_type(4))) float float4v;
typedef __attribute__((ext_vector_type(4))) float v4f;

constexpr int MDIM = 2048;
constexpr int KDIM = 65536;
constexpr int NPL  = 768;      // N per layer
constexpr int LNUM = 2;
constexpr int BM = 128, BN = 128, BK = 32;
constexpr int KSPLIT = 16;
constexpr int KCHUNK = KDIM / KSPLIT;   // 4096
constexpr int NITER  = KCHUNK / BK;     // 128
constexpr int TM = MDIM / BM;           // 16 m-tiles
constexpr int TN = (LNUM * NPL) / BN;   // 12 n-tiles
constexpr int KGRAN = KDIM / 8;         // 8192 k-granules (8 bf16 each)

// Workspace packs (bf16, GEMM-native order):
//   f_pack[mt][g][ (m&127)^(g&3) ][kk]   mt=0..15, g=0..8191
//   W_pack[nt][g][ (n&127)^(g&3) ][kk]   nt=0..11 (nt = layer*6 + d0/128)
// Per (tile, 4-granule K-step) this is one CONTIGUOUS 8 KiB block whose linear
// order equals the swizzled LDS layout -> staged by plain global_load_lds.
constexpr size_t FPACK_SHORTS = (size_t)TM * KGRAN * 128 * 8;  // 256 MiB
constexpr size_t WPACK_SHORTS = (size_t)TN * KGRAN * 128 * 8;  // 192 MiB
constexpr size_t WS_NEEDED = (FPACK_SHORTS + WPACK_SHORTS) * sizeof(short);

// RTNE fp32 -> bf16 bits (identical numerics to previous passing run)
__device__ __forceinline__ short f2bf(float x) {
  unsigned u = __float_as_uint(x);
  u += 0x7fffu + ((u >> 16) & 1u);
  return (short)(u >> 16);
}

__device__ __forceinline__ void gload16(const short* g, short* l) {
  // width=16 direct global->LDS DMA; LDS dest = wave-uniform base + lane*16
  __builtin_amdgcn_global_load_lds(
      (const __attribute__((address_space(1))) void*)g,
      (__attribute__((address_space(3))) void*)l, 16, 0, 0);
}

// out[b][l][d] = bias[l][d]  (overwrites poison; GEMM atomically accumulates)
__global__ void init_out(const float* __restrict__ bias, float* __restrict__ out) {
  int i = blockIdx.x * blockDim.x + threadIdx.x;  // one float4 each
  int idx = i * 4;
  int ld = idx % (LNUM * NPL);
  *(float4v*)(out + idx) = *(const float4v*)(bias + ld);
}

// ---- pack f: [2048][65536] f32 -> f_pack bf16 ----------------------------
// block: 4 m x 64 g (256 threads, 1 granule each). Reads coalesced (16 lanes
// sweep g within a row); writes cover full 64B lines (4-lane m-quads permute
// within the quad under ^g&3).
__global__ __launch_bounds__(256)
void pack_f(const float* __restrict__ f, short* __restrict__ fp) {
  const int b = blockIdx.x;               // 512 m-quads * 128 g-chunks
  const int m = (b >> 7) * 4 + (threadIdx.x & 3);
  const int g = (b & 127) * 64 + (threadIdx.x >> 2);
  const float* src = f + (size_t)m * KDIM + g * 8;
  float4v v0 = *(const float4v*)(src);
  float4v v1 = *(const float4v*)(src + 4);
  short8 pk;
  #pragma unroll
  for (int e = 0; e < 4; ++e) { pk[e] = f2bf(v0[e]); pk[4 + e] = f2bf(v1[e]); }
  const int mt = m >> 7;
  const int mx = (m & 127) ^ (g & 3);
  *(short8*)(fp + (((size_t)mt * KGRAN + g) * 128 + mx) * 8) = pk;
}

// ---- pack W: [2][65536][768] f32 -> W_pack bf16 (k-inner transpose) ------
// thread: one (n, g) granule = 8 k's of one column. Reads: each of the 8
// loads coalesces across 64 consecutive-n lanes (256B). Writes: contiguous
// 1 KiB per wave (nx permutes only within 4-groups).
__global__ __launch_bounds__(256)
void pack_w(const float* __restrict__ W, short* __restrict__ wp) {
  const int b  = blockIdx.x;              // 12 nt * 4096 g-pairs
  const int nt = b >> 12;
  const int g  = (b & 4095) * 2 + (threadIdx.x >> 7);
  const int n  = threadIdx.x & 127;
  const int l  = nt / 6;
  const int d0 = (nt % 6) * 128;
  const float* src = W + ((size_t)l * KDIM + (size_t)g * 8) * NPL + d0 + n;
  short8 pk;
  #pragma unroll
  for (int kk = 0; kk < 8; ++kk) pk[kk] = f2bf(src[(size_t)kk * NPL]);
  const int nx = n ^ (g & 3);
  *(short8*)(wp + (((size_t)nt * KGRAN + g) * 128 + nx) * 8) = pk;
}

// ---- bf16 split-K GEMM from packed ws: m97 structure ---------------------
// Per iter: 4x global_load_lds(16B) + 8x ds_read_b128 + 16x MFMA. No VALU
// conversion, no register staging.
__global__ __launch_bounds__(256)
void gemm_packed(const short* __restrict__ fp, const short* __restrict__ wp,
                 float* __restrict__ out) {
  // XCD-aware swizzle (3072 % 8 == 0 -> bijective): each XCD gets a
  // contiguous bx-fastest chunk -> B-tile reuse lands in its private L2.
  const int lin = blockIdx.x;
  const int swz = (lin & 7) * (TM * TN * KSPLIT / 8) + (lin >> 3);
  const int bx = swz % TM;
  const int by = (swz / TM) % TN;
  const int bz = swz / (TM * TN);

  const int tid  = threadIdx.x;
  const int lane = tid & 63;
  const int wave = tid >> 6;
  const int wm = (wave >> 1) * 64;
  const int wn = (wave & 1) * 64;
  const int layer = by / 6;
  const int d0 = (by % 6) * BN;

  __shared__ short sA[4096];  // [kg][mx][kk] = 8 KiB, arrives pre-swizzled
  __shared__ short sB[4096];

  const short* Asrc = fp + ((size_t)bx * KGRAN + (size_t)bz * (KCHUNK / 8)) * 1024
                         + (size_t)tid * 8;
  const short* Bsrc = wp + ((size_t)by * KGRAN + (size_t)bz * (KCHUNK / 8)) * 1024
                         + (size_t)tid * 8;
  short* ldsA = sA + wave * 512;   // wave-uniform DMA base
  short* ldsB = sB + wave * 512;

  v4f acc[4][4];
  #pragma unroll
  for (int i = 0; i < 4; ++i)
    #pragma unroll
    for (int j = 0; j < 4; ++j)
      acc[i][j] = (v4f){0.f, 0.f, 0.f, 0.f};

  const int kg_r = lane >> 4;
  const int r16  = lane & 15;
  int aoff[4], boff[4];
  #pragma unroll
  for (int t = 0; t < 4; ++t) {
    aoff[t] = (kg_r * 128 + ((wm + t * 16 + r16) ^ kg_r)) * 8;
    boff[t] = (kg_r * 128 + ((wn + t * 16 + r16) ^ kg_r)) * 8;
  }

  for (int it = 0; it < NITER; ++it) {
    __syncthreads();                       // prev iter's fragment reads done
    gload16(Asrc, ldsA);
    gload16(Asrc + 2048, ldsA + 2048);
    gload16(Bsrc, ldsB);
    gload16(Bsrc + 2048, ldsB + 2048);
    Asrc += 4096; Bsrc += 4096;
    __syncthreads();                       // compiler drains vmcnt before barrier

    short8 af[4], bfr[4];
    #pragma unroll
    for (int t = 0; t < 4; ++t) af[t]  = *(const short8*)&sA[aoff[t]];
    #pragma unroll
    for (int t = 0; t < 4; ++t) bfr[t] = *(const short8*)&sB[boff[t]];
    #pragma unroll
    for (int i = 0; i < 4; ++i)
      #pragma unroll
      for (int j = 0; j < 4; ++j)
        acc[i][j] = __builtin_amdgcn_mfma_f32_16x16x32_bf16(af[i], bfr[j], acc[i][j], 0, 0, 0);
  }

  // epilogue: device-scope f32 atomic accumulate. C/D layout: col=lane&15,
  // row=(lane>>4)*4+reg  [m89/m91-verified]
  const int colc = lane & 15;
  const int rowb = (lane >> 4) * 4;
  #pragma unroll
  for (int i = 0; i < 4; ++i) {
    #pragma unroll
    for (int j = 0; j < 4; ++j) {
      const int n = d0 + wn + j * 16 + colc;
      #pragma unroll
      for (int r = 0; r < 4; ++r) {
        const int m = bx * BM + wm + i * 16 + rowb + r;
        unsafeAtomicAdd(&out[((size_t)m * LNUM + layer) * NPL + n], acc[i][j][r]);
      }
    }
  }
}

// ---- fallback: previous fused kernel (used only if ws too small) ---------
__global__ __launch_bounds__(256)
void gemm_split_k(const float* __restrict__ f, const float* __restrict__ W,
                  float* __restrict__ out) {
  const int bx = blockIdx.x;
  const int by = blockIdx.y;
  const int bz = blockIdx.z;
  const int tid = threadIdx.x;
  const int lane = tid & 63;
  const int wave = tid >> 6;
  const int wm = (wave >> 1) * 64;
  const int wn = (wave & 1) * 64;
  const int layer = by / 6;
  const int d0 = (by % 6) * BN;

  const float* __restrict__ Wl = W + (size_t)layer * KDIM * NPL;

  __shared__ __hip_bfloat16 sA[4][BM][8];
  __shared__ __hip_bfloat16 sB[4][BN][8];

  const int a_kq = tid & 7;
  const int a_m  = tid >> 3;
  const float* Aptr = f + (size_t)(bx * BM + a_m) * KDIM + (size_t)bz * KCHUNK + a_kq * 4;

  const int b_n  = tid & 127;
  const int b_kg = tid >> 7;
  const float* Bptr = Wl + (size_t)bz * KCHUNK * NPL + d0 + b_n;

  v4f acc[4][4];
  #pragma unroll
  for (int i = 0; i < 4; ++i)
    #pragma unroll
    for (int j = 0; j < 4; ++j)
      acc[i][j] = (v4f){0.f, 0.f, 0.f, 0.f};

  const int kg_r = lane >> 4;
  const int r16  = lane & 15;

  for (int it = 0; it < NITER; ++it) {
    const size_t koff = (size_t)it * BK;

    float4v av[4];
    #pragma unroll
    for (int p = 0; p < 4; ++p)
      av[p] = *(const float4v*)(Aptr + (size_t)(p * 32) * KDIM + koff);

    float bv[16];
    #pragma unroll
    for (int p = 0; p < 2; ++p) {
      const int kg = b_kg + p * 2;
      #pragma unroll
      for (int j = 0; j < 8; ++j)
        bv[p * 8 + j] = Bptr[(koff + (size_t)(kg * 8 + j)) * NPL];
    }

    __syncthreads();

    {
      const int kg = a_kq >> 1;
      const int half = (a_kq & 1) * 4;
      #pragma unroll
      for (int p = 0; p < 4; ++p) {
        const int m = a_m + p * 32;
        short4v pk;
        #pragma unroll
        for (int e = 0; e < 4; ++e) pk[e] = f2bf(av[p][e]);
        *(short4v*)&sA[kg][m ^ kg][half] = pk;
      }
    }
    #pragma unroll
    for (int p = 0; p < 2; ++p) {
      const int kg = b_kg + p * 2;
      short8 pk;
      #pragma unroll
      for (int j = 0; j < 8; ++j) pk[j] = f2bf(bv[p * 8 + j]);
      *(short8*)&sB[kg][b_n ^ kg][0] = pk;
    }

    __syncthreads();

    short8 af[4], bfr[4];
    #pragma unroll
    for (int t = 0; t < 4; ++t)
      af[t] = *(const short8*)&sA[kg_r][(wm + t * 16 + r16) ^ kg_r][0];
    #pragma unroll
    for (int t = 0; t < 4; ++t)
      bfr[t] = *(const short8*)&sB[kg_r][(wn + t * 16 + r16) ^ kg_r][0];
    #pragma unroll
    for (int i = 0; i < 4; ++i)
      #pragma unroll
      for (int j = 0; j < 4; ++j)
        acc[i][j] = __builtin_amdgcn_mfma_f32_16x16x32_bf16(af[i], bfr[j], acc[i][j], 0, 0, 0);
  }

  const int colc = lane & 15;
  const int rowb = (lane >> 4) * 4;
  #pragma unroll
  for (int i = 0; i < 4; ++i) {
    #pragma unroll
    for (int j = 0; j < 4; ++j) {
      const int n = d0 + wn + j * 16 + colc;
      #pragma unroll
      for (int r = 0; r < 4; ++r) {
        const int m = bx * BM + wm + i * 16 + rowb + r;
        unsafeAtomicAdd(&out[((size_t)m * LNUM + layer) * NPL + n], acc[i][j][r]);
      }
    }
  }
}

extern "C" void kernel_launch(void* const* d_in, const int* in_sizes, int n_in,
                              void* d_out, int out_size, void* d_ws, size_t ws_size,
                              hipStream_t stream) {
  const float* f    = (const float*)d_in[0];
  const float* W    = (const float*)d_in[1];
  const float* bias = (const float*)d_in[2];
  float* out = (float*)d_out;

  // out_size = 2048*2*768 = 3145728 floats = 786432 float4s
  init_out<<<dim3(786432 / 256), 256, 0, stream>>>(bias, out);

  if (ws_size >= WS_NEEDED) {
    short* fpk = (short*)d_ws;
    short* wpk = fpk + FPACK_SHORTS;
    pack_f<<<dim3(512 * 128), 256, 0, stream>>>(f, fpk);
    pack_w<<<dim3(TN * 4096), 256, 0, stream>>>(W, wpk);
    gemm_packed<<<dim3(TM * TN * KSPLIT), 256, 0, stream>>>(fpk, wpk, out);
  } else {
    gemm_split_k<<<dim3(TM, TN, KSPLIT), 256, 0, stream>>>(f, W, out);
  }
}